// Round 8
// baseline (229.283 us; speedup 1.0000x reference)
//
#include <hip/hip_runtime.h>
#include <math.h>

#define T_TOTAL 16384
#define HDIM    2048
#define NEXP    64

typedef unsigned short ushort_t;
using bf16x8 = __attribute__((ext_vector_type(8))) short;
using f32x4  = __attribute__((ext_vector_type(4))) float;

// ---------------------------------------------------------------------------
// fp32 -> bf16 split: x = hi + mid + lo, residuals exact in fp32. With the
// 8-term contraction (all but ll) the dropped error is ~2^-36 |x||w|.
// ---------------------------------------------------------------------------
__device__ __forceinline__ unsigned cvtpk_bf16(float a, float b) {
    unsigned r;
    asm("v_cvt_pk_bf16_f32 %0, %1, %2" : "=v"(r) : "v"(a), "v"(b));
    return r;
}

__device__ __forceinline__ void split8(const float4 a, const float4 b,
                                       bf16x8& h, bf16x8& m, bf16x8& l) {
    const float f[8] = {a.x, a.y, a.z, a.w, b.x, b.y, b.z, b.w};
    union { unsigned u[4]; bf16x8 v; } H, M, L;
#pragma unroll
    for (int d = 0; d < 4; ++d) {
        const float f0 = f[2*d], f1 = f[2*d+1];
        const unsigned ph = cvtpk_bf16(f0, f1);
        const float r0 = f0 - __uint_as_float(ph << 16);
        const float r1 = f1 - __uint_as_float(ph & 0xFFFF0000u);
        const unsigned pm = cvtpk_bf16(r0, r1);
        const float s0 = r0 - __uint_as_float(pm << 16);
        const float s1 = r1 - __uint_as_float(pm & 0xFFFF0000u);
        H.u[d] = ph;
        M.u[d] = pm;
        L.u[d] = cvtpk_bf16(s0, s1);
    }
    h = H.v; m = M.v; l = L.v;
}

// async global->LDS, 16B per lane: src PER-LANE, dst = uniform base + 16*lane
__device__ __forceinline__ void load_lds16(const void* g, void* lds) {
    __builtin_amdgcn_global_load_lds(
        (const __attribute__((address_space(1))) unsigned int*)g,
        (__attribute__((address_space(3))) unsigned int*)lds, 16, 0, 0);
}

// X staging swizzle: bijective on 16 chunks, same function on write & read
__device__ __forceinline__ int xswz(int row) {
    return ((row & 7) << 1) | ((row >> 3) & 1);
}

// ---------------------------------------------------------------------------
// W conversion: W[64][2048] fp32 -> bf16x3 planes, pre-tiled per 64-k chunk
// and pre-swizzled: wt[kc][plane][e][c ^ (e&7)] = bf16_plane(w[e][kc*64+c*8..+8])
// so GEMM staging is a pure linear 24 KB copy per k-chunk.
// ---------------------------------------------------------------------------
__global__ __launch_bounds__(256)
void convert_w_kernel(const float* __restrict__ w, ushort_t* __restrict__ wt)
{
    const int idx = blockIdx.x * 256 + threadIdx.x;   // grid 64x256 = 16384
    const int e   = idx >> 8;                         // 0..63
    const int c8  = idx & 255;
    const int kc  = c8 >> 3;                          // 0..31
    const int c   = c8 & 7;                           // 0..7

    const float* src = w + (size_t)e * HDIM + kc * 64 + c * 8;
    const float4 v0 = *(const float4*)(src);
    const float4 v1 = *(const float4*)(src + 4);
    bf16x8 H, M, L;
    split8(v0, v1, H, M, L);

    const int slot = c ^ (e & 7);
    bf16x8* base = (bf16x8*)wt;
    base[((size_t)(kc * 3 + 0) * 64 + e) * 8 + slot] = H;
    base[((size_t)(kc * 3 + 1) * 64 + e) * 8 + slot] = M;
    base[((size_t)(kc * 3 + 2) * 64 + e) * 8 + slot] = L;
}

// ---------------------------------------------------------------------------
// FUSED router, round-8: identical memory structure to r7 (all global
// accesses lane-contiguous), numerics hardened:
//   - kc loop hand-unrolled by 2 -> acc split into 8 static chains
//     acc[parity][ks][n], each 128 sequential MFMA-accumulates (r6-passing
//     regime was 96), pairwise tree-summed in the epilogue.
//   - 8 bf16x6->bf16x8 terms (hh,mh,hm,mm,lh,hl,lm,ml): dropped error 2^-36.
// Grid 512 x 256 (4 waves), block = 32 tok x 64 exp x full K, BK=64,
// double-buffered LDS, one barrier per k-chunk (implicit vmcnt(0) drain).
// ---------------------------------------------------------------------------
__global__ __launch_bounds__(256, 2)
void router_fused(const float* __restrict__ x,
                  const ushort_t* __restrict__ wt,
                  const float* __restrict__ bias,
                  float* __restrict__ out_scores,
                  float* __restrict__ out_idx)
{
    __shared__ __align__(16) float    Xs[2][32 * 64];       // 16 KB
    __shared__ __align__(16) ushort_t Ws[2][3 * 64 * 64];   // 48 KB

    const int tid  = threadIdx.x;
    const int wv   = tid >> 6;
    const int lane = tid & 63;
    const int t0   = blockIdx.x * 32;
    const int a    = wv >> 1;            // M-tile (16 tokens)
    const int b    = wv & 1;             // expert half (32 experts)
    const int lr   = lane & 15;
    const int lg   = lane >> 4;

    const float bv = bias[lane];

    // X staging addressing: instr q covers 4 rows x 16 chunks; per-lane
    // source chunk pre-swizzled by xswz(row) (rule 21: linear LDS dest)
    const int xrow0 = wv * 8 + (lane >> 4);
    const int xrow1 = xrow0 + 4;
    const float* xsrc0 = x + (size_t)(t0 + xrow0) * HDIM + ((lane & 15) ^ xswz(xrow0)) * 4;
    const float* xsrc1 = x + (size_t)(t0 + xrow1) * HDIM + ((lane & 15) ^ xswz(xrow1)) * 4;

    // W staging: pure linear lane-contiguous copy of the pre-tiled planes
    const ushort_t* wsrc = wt + (size_t)(wv * 6) * 512 + lane * 8;

    f32x4 acc[8];                        // [parity][ks][n], all-static indices
#pragma unroll
    for (int i = 0; i < 8; ++i) {
        f32x4 z = {0.0f, 0.0f, 0.0f, 0.0f};
        acc[i] = z;
    }

    const int rowX = a * 16 + lr;
    const int swzX = xswz(rowX);

    auto stage = [&](int kc, int bi) {
        const int ko = kc * 64;                              // floats
        load_lds16(xsrc0 + ko, &Xs[bi][(wv * 2 + 0) * 256]);
        load_lds16(xsrc1 + ko, &Xs[bi][(wv * 2 + 1) * 256]);
        const ushort_t* wn = wsrc + (size_t)kc * 12288;
#pragma unroll
        for (int q = 0; q < 6; ++q)
            load_lds16(wn + q * 512, &Ws[bi][(wv * 6 + q) * 512]);
    };

#define COMPUTE(BI, PAR) do {                                                 \
    const float*  rb  = &Xs[BI][rowX * 64];                                   \
    const bf16x8* wbp = (const bf16x8*)&Ws[BI][0];                            \
    _Pragma("unroll")                                                         \
    for (int ks = 0; ks < 2; ++ks) {                                          \
        const int g0 = ks * 8 + lg * 2;                                       \
        const float4 c0 = *(const float4*)(rb + ((g0       ^ swzX) * 4));     \
        const float4 c1 = *(const float4*)(rb + (((g0 + 1) ^ swzX) * 4));     \
        bf16x8 Ah, Am, Al;                                                    \
        split8(c0, c1, Ah, Am, Al);                                           \
        _Pragma("unroll")                                                     \
        for (int n = 0; n < 2; ++n) {                                         \
            const int e    = b * 32 + n * 16 + lr;                            \
            const int slot = (ks * 4 + lg) ^ (e & 7);                         \
            const bf16x8 Bh = wbp[(0 * 64 + e) * 8 + slot];                   \
            const bf16x8 Bm = wbp[(1 * 64 + e) * 8 + slot];                   \
            const bf16x8 Bl = wbp[(2 * 64 + e) * 8 + slot];                   \
            f32x4 t = acc[(PAR) * 4 + ks * 2 + n];                            \
            t = __builtin_amdgcn_mfma_f32_16x16x32_bf16(Ah, Bh, t, 0, 0, 0);  \
            t = __builtin_amdgcn_mfma_f32_16x16x32_bf16(Am, Bh, t, 0, 0, 0);  \
            t = __builtin_amdgcn_mfma_f32_16x16x32_bf16(Ah, Bm, t, 0, 0, 0);  \
            t = __builtin_amdgcn_mfma_f32_16x16x32_bf16(Am, Bm, t, 0, 0, 0);  \
            t = __builtin_amdgcn_mfma_f32_16x16x32_bf16(Al, Bh, t, 0, 0, 0);  \
            t = __builtin_amdgcn_mfma_f32_16x16x32_bf16(Ah, Bl, t, 0, 0, 0);  \
            t = __builtin_amdgcn_mfma_f32_16x16x32_bf16(Al, Bm, t, 0, 0, 0);  \
            t = __builtin_amdgcn_mfma_f32_16x16x32_bf16(Am, Bl, t, 0, 0, 0);  \
            acc[(PAR) * 4 + ks * 2 + n] = t;                                  \
        }                                                                     \
    }                                                                         \
} while (0)

    // ---- prologue: stage kc=0 into buf 0 ----
    stage(0, 0);
    __syncthreads();

#pragma unroll 1
    for (int j = 0; j < 16; ++j) {
        const int kc0 = j * 2;
        // even half: stage kc0+1 -> buf1, compute kc0 from buf0
        stage(kc0 + 1, 1);
        COMPUTE(0, 0);
        __syncthreads();                 // drains DMA -> buf1 ready
        // odd half: stage kc0+2 -> buf0, compute kc0+1 from buf1
        if (kc0 + 2 < 32) stage(kc0 + 2, 0);
        COMPUTE(1, 1);
        __syncthreads();                 // drains DMA -> buf0 ready
    }
#undef COMPUTE

    // ---- epilogue: tree-sum the 4 chains per n, overlay, top-8 ----
    float* ov = &Xs[0][0];               // 32 tok x 64 exp (barrier passed)
#pragma unroll
    for (int n = 0; n < 2; ++n) {
        const f32x4 s = (acc[0 * 4 + 0 * 2 + n] + acc[0 * 4 + 1 * 2 + n])
                      + (acc[1 * 4 + 0 * 2 + n] + acc[1 * 4 + 1 * 2 + n]);
#pragma unroll
        for (int r = 0; r < 4; ++r) {
            const int t = a * 16 + lg * 4 + r;
            const int e = b * 32 + n * 16 + lr;
            ov[t * 64 + e] = s[r];
        }
    }
    __syncthreads();

#pragma unroll 1
    for (int i = 0; i < 8; ++i) {
        const int t = wv * 8 + i;
        const float logit = ov[t * 64 + lane];

        const float score = 1.0f / (1.0f + expf(-logit));
        float key = score + bv;

        float myscore = 0.0f;
        int   myidx   = 0;
        float denom   = 0.0f;

#pragma unroll
        for (int r = 0; r < 8; ++r) {
            float bk = key;
#pragma unroll
            for (int off = 32; off > 0; off >>= 1)
                bk = fmaxf(bk, __shfl_xor(bk, off));
            const unsigned long long msk = __ballot(key == bk);
            const int bi = __ffsll((long long)msk) - 1;   // lowest tied idx
            const float wsc = __shfl(score, bi);          // raw winner score
            denom += wsc;
            if (lane == r)  { myscore = wsc; myidx = bi; }
            if (lane == bi) key = -__builtin_inff();
        }

        const float factor = 2.5f / (denom + 1e-20f);
        if (lane < 8) {
            out_scores[(size_t)(t0 + t) * 8 + lane] = myscore * factor;
            out_idx  [(size_t)(t0 + t) * 8 + lane] = (float)myidx;
        }
    }
}

// ---------------------------------------------------------------------------
// Correctness-only fallback (tiny workspace): naive dot + one-wave topk.
// ---------------------------------------------------------------------------
__global__ void router_gemm_naive(const float* __restrict__ x,
                                  const float* __restrict__ w,
                                  float* __restrict__ partial)
{
    const int t = blockIdx.x;
    const int e = threadIdx.x;          // 64 threads
    const float* xp = x + (size_t)t * HDIM;
    const float* wp = w + (size_t)e * HDIM;
    float s = 0.0f;
    for (int k = 0; k < HDIM; ++k) s = fmaf(xp[k], wp[k], s);
    partial[(size_t)t * NEXP + e] = s;
}

__global__ __launch_bounds__(256)
void router_topk_naive(const float* __restrict__ partial,
                       const float* __restrict__ bias,
                       float* __restrict__ out_scores,
                       float* __restrict__ out_idx)
{
    const int token = blockIdx.x * 4 + (threadIdx.x >> 6);
    const int lane  = threadIdx.x & 63;
    const float logit = partial[(size_t)token * NEXP + lane];
    const float score = 1.0f / (1.0f + expf(-logit));
    float key = score + bias[lane];
    float myscore = 0.0f; int myidx = 0; float denom = 0.0f;
#pragma unroll
    for (int r = 0; r < 8; ++r) {
        float bk = key;
#pragma unroll
        for (int off = 32; off > 0; off >>= 1)
            bk = fmaxf(bk, __shfl_xor(bk, off));
        const unsigned long long msk = __ballot(key == bk);
        const int bi = __ffsll((long long)msk) - 1;
        const float wsc = __shfl(score, bi);
        denom += wsc;
        if (lane == r)  { myscore = wsc; myidx = bi; }
        if (lane == bi) key = -__builtin_inff();
    }
    const float factor = 2.5f / (denom + 1e-20f);
    if (lane < 8) {
        out_scores[(size_t)token * 8 + lane] = myscore * factor;
        out_idx  [(size_t)token * 8 + lane] = (float)myidx;
    }
}

// ---------------------------------------------------------------------------
extern "C" void kernel_launch(void* const* d_in, const int* in_sizes, int n_in,
                              void* d_out, int out_size, void* d_ws, size_t ws_size,
                              hipStream_t stream)
{
    const float* x    = (const float*)d_in[0];   // [4,4096,2048] f32
    const float* bias = (const float*)d_in[1];   // [64] f32
    const float* w    = (const float*)d_in[2];   // [64,2048] f32

    float* out = (float*)d_out;

    const size_t wtBytes = (size_t)3 * NEXP * HDIM * sizeof(ushort_t);  // 768 KB

    if (ws_size >= wtBytes) {
        ushort_t* wt = (ushort_t*)d_ws;
        convert_w_kernel<<<dim3(64), dim3(256), 0, stream>>>(w, wt);
        router_fused<<<dim3(T_TOTAL / 32), dim3(256), 0, stream>>>(
            x, wt, bias, out, out + (size_t)T_TOTAL * 8);
    } else {
        float* partial = (float*)d_ws;           // needs 4 MiB
        router_gemm_naive<<<dim3(T_TOTAL), dim3(64), 0, stream>>>(x, w, partial);
        router_topk_naive<<<dim3(T_TOTAL / 4), dim3(256), 0, stream>>>(
            partial, bias, out, out + (size_t)T_TOTAL * 8);
    }
}